// Round 12
// baseline (131.559 us; speedup 1.0000x reference)
//
#include <hip/hip_runtime.h>
#include <hip/hip_bf16.h>

// GQA prefill: B=2 T=2048 DM=768 H=12 HKV=4 DH=64 WIN=512 GLB=64
// MEASUREMENT ROUND: round-9 structure (best: 128x64 GEMMs, zero-shuffle attn)
// with REPS=2 idempotent body repetition in every kernel to split per-kernel
// time vs inter-launch gaps:  gaps = 2*61.7 - dur2,  sum_kernels = dur2 - 61.7.

typedef __attribute__((ext_vector_type(8))) short bf16x8;
typedef __attribute__((ext_vector_type(4))) short bf16x4;
typedef __attribute__((ext_vector_type(4))) float f32x4;
typedef __attribute__((ext_vector_type(4))) unsigned short u16x4;

#define MFMA   __builtin_amdgcn_mfma_f32_16x16x32_bf16
#define MFMA16 __builtin_amdgcn_mfma_f32_16x16x16bf16_1k

constexpr int REPS = 2;   // measurement: 2x idempotent work per kernel
constexpr int BB = 2, TT = 2048, DM = 768, HH = 12, HKV = 4, DH = 64;
constexpr int WIN = 512, GLB = 64;
constexpr float SC2 = 0.18033688011112042f; // 0.125 * log2(e)

__device__ __forceinline__ unsigned short f2b(float f) {
    union { float f; unsigned int u; } v; v.f = f;
    unsigned int r = v.u + 0x7fffu + ((v.u >> 16) & 1u);
    return (unsigned short)(r >> 16);
}

#define GLOAD_LDS(gp, lp)                                                      \
    __builtin_amdgcn_global_load_lds(                                          \
        (const __attribute__((address_space(1))) void*)(gp),                   \
        (__attribute__((address_space(3))) void*)(lp), 16, 0, 0)

// ---------- fused prep: x->bf16 (0..3071), rope (3072..3327), W^T (3328..4863)
__global__ __launch_bounds__(256) void k_pre(const float* __restrict__ x,
                                             unsigned short* __restrict__ xb,
                                             float2* __restrict__ rope,
                                             const float* __restrict__ wq,
                                             const float* __restrict__ wk,
                                             const float* __restrict__ wv,
                                             const float* __restrict__ wo,
                                             unsigned short* __restrict__ wqT,
                                             unsigned short* __restrict__ wkT,
                                             unsigned short* __restrict__ wvT,
                                             unsigned short* __restrict__ woT) {
    __shared__ float t[32][33];
    int bid = blockIdx.x, tid = threadIdx.x;
    for (int rep = 0; rep < REPS; ++rep) {
        if (bid < 3072) {
            int i = bid * 256 + tid;
            float4 v = ((const float4*)x)[i];
            u16x4 o; o.x = f2b(v.x); o.y = f2b(v.y); o.z = f2b(v.z); o.w = f2b(v.w);
            ((u16x4*)xb)[i] = o;
        } else if (bid < 3328) {
            int i = (bid - 3072) * 256 + tid;  // T*32
            int tt = i >> 5, p = i & 31;
            float inv = exp2f(-(float)p * (13.287712379549449f / 32.0f));
            float ang = (float)tt * inv;
            rope[i] = make_float2(cosf(ang), sinf(ang));
        } else {
            int wb = bid - 3328;
            const float* src; unsigned short* dst; int N, tile;
            if (wb < 576)      { src = wq; dst = wqT; N = 768; tile = wb; }
            else if (wb < 768) { src = wk; dst = wkT; N = 256; tile = wb - 576; }
            else if (wb < 960) { src = wv; dst = wvT; N = 256; tile = wb - 768; }
            else               { src = wo; dst = woT; N = 768; tile = wb - 960; }
            int ntiles = N / 32;
            int k0 = (tile / ntiles) * 32, n0 = (tile % ntiles) * 32;
            int tx = tid & 31, ty = tid >> 5;
            #pragma unroll
            for (int e = 0; e < 4; ++e) {
                int r = ty + e * 8;
                t[r][tx] = src[(size_t)(k0 + r) * N + n0 + tx];
            }
            __syncthreads();
            #pragma unroll
            for (int e = 0; e < 4; ++e) {
                int r = ty + e * 8;
                dst[(size_t)(n0 + r) * DM + k0 + tx] = f2b(t[tx][r]);
            }
            __syncthreads();
        }
    }
}

// ---------- fused QKV GEMM: 128x64 tile, BK=64, 12 steps, XOR-swizzled LDS.
__global__ __launch_bounds__(256) void k_qkv(const unsigned short* __restrict__ xb,
                                             const unsigned short* __restrict__ wqT,
                                             const unsigned short* __restrict__ wkT,
                                             const unsigned short* __restrict__ wvT,
                                             unsigned short* __restrict__ qb,
                                             unsigned short* __restrict__ kb,
                                             unsigned short* __restrict__ vtb,
                                             const float2* __restrict__ rope) {
    __shared__ __align__(16) unsigned short Ab[2][128 * 64];
    __shared__ __align__(16) unsigned short Bb[2][64 * 64];
    const int tid = threadIdx.x;
    const int wave = tid >> 6, lane = tid & 63;
    const int quad = lane >> 4, col = lane & 15;
    const int y = blockIdx.y;
    int mode, hl;
    const unsigned short* Bt;
    if (y < 12)      { mode = 0; hl = y;      Bt = wqT + (size_t)hl * 64 * DM; }
    else if (y < 16) { mode = 1; hl = y - 12; Bt = wkT + (size_t)hl * 64 * DM; }
    else             { mode = 2; hl = y - 16; Bt = wvT + (size_t)hl * 64 * DM; }
    const int m0b = blockIdx.x * 128;

    const int rg = lane >> 3;
    const int cg = (lane & 7) ^ rg;
    const int ck = col & 7;

    auto stage = [&](int buf, int k) {
        #pragma unroll
        for (int m = 0; m < 4; ++m) {
            int g = wave * 4 + m;
            GLOAD_LDS(xb + (size_t)(m0b + g * 8 + rg) * DM + k + cg * 8,
                      &Ab[buf][g * 512]);
        }
        #pragma unroll
        for (int m = 0; m < 2; ++m) {
            int g = wave * 2 + m;
            GLOAD_LDS(Bt + (size_t)(g * 8 + rg) * DM + k + cg * 8,
                      &Bb[buf][g * 512]);
        }
    };

    const int arow0 = (wave * 32 + col) * 64;
    const int arow1 = (wave * 32 + 16 + col) * 64;

    for (int rep = 0; rep < REPS; ++rep) {
        f32x4 acc[2][4];
        #pragma unroll
        for (int rt = 0; rt < 2; ++rt)
            #pragma unroll
            for (int j = 0; j < 4; ++j) acc[rt][j] = f32x4{0.f, 0.f, 0.f, 0.f};

        stage(0, 0);
        __syncthreads();

        for (int t = 0; t < 12; ++t) {
            const int buf = t & 1;
            if (t < 11) stage(buf ^ 1, (t + 1) * 64);
            __builtin_amdgcn_s_setprio(1);
            #pragma unroll
            for (int ks = 0; ks < 2; ++ks) {
                const int p = ((ks * 4 + quad) ^ ck) * 8;
                bf16x8 a0 = *(const bf16x8*)&Ab[buf][arow0 + p];
                bf16x8 a1 = *(const bf16x8*)&Ab[buf][arow1 + p];
                #pragma unroll
                for (int j = 0; j < 4; ++j) {
                    bf16x8 b = *(const bf16x8*)&Bb[buf][(j * 16 + col) * 64 + p];
                    acc[0][j] = MFMA(a0, b, acc[0][j], 0, 0, 0);
                    acc[1][j] = MFMA(a1, b, acc[1][j], 0, 0, 0);
                }
            }
            __builtin_amdgcn_s_setprio(0);
            __syncthreads();
        }

        if (mode == 2) {
            int b = m0b >> 11;
            #pragma unroll
            for (int j = 0; j < 4; ++j)
                #pragma unroll
                for (int rt = 0; rt < 2; ++rt)
                    #pragma unroll
                    for (int r = 0; r < 4; ++r) {
                        int m = m0b + wave * 32 + rt * 16 + quad * 4 + r;
                        int t = m & (TT - 1);
                        int d = j * 16 + col;
                        vtb[((size_t)(b * HKV + hl) * DH + d) * TT + t] = f2b(acc[rt][j][r]);
                    }
        } else {
            int nheads = (mode == 0) ? HH : HKV;
            unsigned short* ob = (mode == 0) ? qb : kb;
            #pragma unroll
            for (int rt = 0; rt < 2; ++rt)
                #pragma unroll
                for (int r = 0; r < 4; ++r) {
                    int m = m0b + wave * 32 + rt * 16 + quad * 4 + r;
                    int t = m & (TT - 1);
                    int b = m >> 11;
                    float2 cs0 = rope[t * 32 + col];
                    float2 cs1 = rope[t * 32 + 16 + col];
                    float v0 = acc[rt][0][r], v1 = acc[rt][1][r], v2 = acc[rt][2][r], v3 = acc[rt][3][r];
                    unsigned short* dst = ob + ((size_t)(b * nheads + hl) * TT + t) * DH + col;
                    dst[0]  = f2b(v0 * cs0.x - v2 * cs0.y);
                    dst[16] = f2b(v1 * cs1.x - v3 * cs1.y);
                    dst[32] = f2b(v2 * cs0.x + v0 * cs0.y);
                    dst[48] = f2b(v3 * cs1.x + v1 * cs1.y);
                }
        }
    }
}

// ---------- output projection GEMM (f32 out), same structure
__global__ __launch_bounds__(256) void k_out(const unsigned short* __restrict__ ao,
                                             const unsigned short* __restrict__ woT,
                                             float* __restrict__ out) {
    __shared__ __align__(16) unsigned short Ab[2][128 * 64];
    __shared__ __align__(16) unsigned short Bb[2][64 * 64];
    const int tid = threadIdx.x;
    const int wave = tid >> 6, lane = tid & 63;
    const int quad = lane >> 4, col = lane & 15;
    const int m0b = blockIdx.x * 128;
    const int n0 = blockIdx.y * 64;

    const int rg = lane >> 3;
    const int cg = (lane & 7) ^ rg;
    const int ck = col & 7;

    auto stage = [&](int buf, int k) {
        #pragma unroll
        for (int m = 0; m < 4; ++m) {
            int g = wave * 4 + m;
            GLOAD_LDS(ao + (size_t)(m0b + g * 8 + rg) * DM + k + cg * 8,
                      &Ab[buf][g * 512]);
        }
        #pragma unroll
        for (int m = 0; m < 2; ++m) {
            int g = wave * 2 + m;
            GLOAD_LDS(woT + (size_t)(n0 + g * 8 + rg) * DM + k + cg * 8,
                      &Bb[buf][g * 512]);
        }
    };

    const int arow0 = (wave * 32 + col) * 64;
    const int arow1 = (wave * 32 + 16 + col) * 64;

    for (int rep = 0; rep < REPS; ++rep) {
        f32x4 acc[2][4];
        #pragma unroll
        for (int rt = 0; rt < 2; ++rt)
            #pragma unroll
            for (int j = 0; j < 4; ++j) acc[rt][j] = f32x4{0.f, 0.f, 0.f, 0.f};

        stage(0, 0);
        __syncthreads();

        for (int t = 0; t < 12; ++t) {
            const int buf = t & 1;
            if (t < 11) stage(buf ^ 1, (t + 1) * 64);
            __builtin_amdgcn_s_setprio(1);
            #pragma unroll
            for (int ks = 0; ks < 2; ++ks) {
                const int p = ((ks * 4 + quad) ^ ck) * 8;
                bf16x8 a0 = *(const bf16x8*)&Ab[buf][arow0 + p];
                bf16x8 a1 = *(const bf16x8*)&Ab[buf][arow1 + p];
                #pragma unroll
                for (int j = 0; j < 4; ++j) {
                    bf16x8 b = *(const bf16x8*)&Bb[buf][(j * 16 + col) * 64 + p];
                    acc[0][j] = MFMA(a0, b, acc[0][j], 0, 0, 0);
                    acc[1][j] = MFMA(a1, b, acc[1][j], 0, 0, 0);
                }
            }
            __builtin_amdgcn_s_setprio(0);
            __syncthreads();
        }

        #pragma unroll
        for (int rt = 0; rt < 2; ++rt)
            #pragma unroll
            for (int j = 0; j < 4; ++j)
                #pragma unroll
                for (int r = 0; r < 4; ++r) {
                    int m = m0b + wave * 32 + rt * 16 + quad * 4 + r;
                    out[(size_t)m * DM + n0 + j * 16 + col] = acc[rt][j][r];
                }
    }
}

// ---------- flash attention: 4 waves x 16 q-rows, gload_lds KV staging,
// swapped QK^T, zero-shuffle PV (round-9 structure).
__global__ __launch_bounds__(256) void k_attn(const unsigned short* __restrict__ Q,
                                              const unsigned short* __restrict__ K,
                                              const unsigned short* __restrict__ Vt,
                                              unsigned short* __restrict__ AO) {
    __shared__ __align__(16) unsigned short kbuf[2][64 * 64]; // [buf][j][d] 8KB
    __shared__ __align__(16) unsigned short vbuf[2][64 * 64]; // [buf][d][j] 8KB
    const int lane = threadIdx.x & 63;
    const int wave = threadIdx.x >> 6;
    const int quad = lane >> 4, col = lane & 15;
    const int lbid = (blockIdx.x & 7) * 96 + (blockIdx.x >> 3);
    const int qb = lbid & 31, bh = lbid >> 5;
    const int h = bh % HH, b = bh / HH;
    const int hkv = h / 3;
    const int i0 = qb * 64 + wave * 16;
    const int irow = i0 + col;

    const unsigned short* qbase = Q + ((size_t)(b * HH + h) * TT + irow) * DH + quad * 8;
    const bf16x8 qf0 = *(const bf16x8*)qbase;
    const bf16x8 qf1 = *(const bf16x8*)(qbase + 32);
    const unsigned short* kbase = K + (size_t)(b * HKV + hkv) * TT * DH;
    const unsigned short* vbase = Vt + (size_t)(b * HKV + hkv) * DH * TT;

    int jw0 = (qb * 64 - WIN + 1) & ~63; if (jw0 < 64) jw0 = 64;
    const int jlast = qb * 64;
    const int nt = 1 + ((jlast >= 64) ? (((jlast - jw0) >> 6) + 1) : 0);
    auto j0_of = [&](int t) { return (t == 0) ? 0 : (jw0 + ((t - 1) << 6)); };

    const int sr = lane >> 3;
    const int soff = ((lane & 7) ^ sr) * 8;
    const int ck = col & 7;

    auto stage = [&](int bb, int j0) {
        GLOAD_LDS(kbase + (size_t)(j0 + wave * 16 + sr) * DH + soff,
                  &kbuf[bb][(wave * 16) * 64]);
        GLOAD_LDS(kbase + (size_t)(j0 + wave * 16 + 8 + sr) * DH + soff,
                  &kbuf[bb][(wave * 16 + 8) * 64]);
        GLOAD_LDS(vbase + (size_t)(wave * 16 + sr) * TT + j0 + soff,
                  &vbuf[bb][(wave * 16) * 64]);
        GLOAD_LDS(vbase + (size_t)(wave * 16 + 8 + sr) * TT + j0 + soff,
                  &vbuf[bb][(wave * 16 + 8) * 64]);
    };

    for (int rep = 0; rep < REPS; ++rep) {
        float m_run = -1e30f, l_lane = 0.f;
        f32x4 accO[4];
        #pragma unroll
        for (int dt = 0; dt < 4; ++dt) accO[dt] = f32x4{0.f, 0.f, 0.f, 0.f};

        stage(0, 0);
        __syncthreads();

        for (int t = 0; t < nt; ++t) {
            const int bb = t & 1;
            if (t + 1 < nt) stage(bb ^ 1, j0_of(t + 1));

            const int j0 = j0_of(t);
            const int mode = (t == 0) ? ((i0 < 64) ? 1 : 0)
                           : (((j0 + 63 > i0) || (j0 <= i0 + 15 - WIN)) ? 2 : 0);

            f32x4 sT[4];
            #pragma unroll
            for (int f = 0; f < 4; ++f) sT[f] = f32x4{0.f, 0.f, 0.f, 0.f};
            __builtin_amdgcn_s_setprio(1);
            #pragma unroll
            for (int f = 0; f < 4; ++f) {
                bf16x8 k0 = *(const bf16x8*)&kbuf[bb][(f * 16 + col) * 64 + (quad ^ ck) * 8];
                bf16x8 k1 = *(const bf16x8*)&kbuf[bb][(f * 16 + col) * 64 + ((4 + quad) ^ ck) * 8];
                sT[f] = MFMA(k0, qf0, sT[f], 0, 0, 0);
                sT[f] = MFMA(k1, qf1, sT[f], 0, 0, 0);
            }
            __builtin_amdgcn_s_setprio(0);

            const int dq = irow - j0 - quad * 4;
            if (mode == 1) {
                #pragma unroll
                for (int f = 0; f < 4; ++f)
                    #pragma unroll
                    for (int r = 0; r < 4; ++r)
                        if (dq - f * 16 - r < 0) sT[f][r] = -3e30f;
            } else if (mode == 2) {
                #pragma unroll
                for (int f = 0; f < 4; ++f)
                    #pragma unroll
                    for (int r = 0; r < 4; ++r)
                        if ((unsigned)(dq - f * 16 - r) >= (unsigned)WIN) sT[f][r] = -3e30f;
            }

            float mx = -3e30f;
            #pragma unroll
            for (int f = 0; f < 4; ++f)
                #pragma unroll
                for (int r = 0; r < 4; ++r) mx = fmaxf(mx, sT[f][r]);

            if (!__all(mx <= m_run + 44.f)) {
                float rm = fmaxf(mx, __shfl_xor(mx, 16));
                rm = fmaxf(rm, __shfl_xor(rm, 32));
                float mn = fmaxf(m_run, rm);
                float corr = exp2f((m_run - mn) * SC2);
                m_run = mn;
                l_lane *= corr;
                #pragma unroll
                for (int dt = 0; dt < 4; ++dt)
                    #pragma unroll
                    for (int r = 0; r < 4; ++r) accO[dt][r] *= corr;
            }

            const float mbase = m_run * SC2;
            unsigned int pk[4][2];
            float ps = 0.f;
            #pragma unroll
            for (int f = 0; f < 4; ++f) {
                float p0 = exp2f(__builtin_fmaf(sT[f][0], SC2, -mbase));
                float p1 = exp2f(__builtin_fmaf(sT[f][1], SC2, -mbase));
                float p2 = exp2f(__builtin_fmaf(sT[f][2], SC2, -mbase));
                float p3 = exp2f(__builtin_fmaf(sT[f][3], SC2, -mbase));
                ps += (p0 + p1) + (p2 + p3);
                asm("v_cvt_pk_bf16_f32 %0, %1, %2" : "=v"(pk[f][0]) : "v"(p0), "v"(p1));
                asm("v_cvt_pk_bf16_f32 %0, %1, %2" : "=v"(pk[f][1]) : "v"(p2), "v"(p3));
            }
            l_lane += ps;

            __builtin_amdgcn_s_setprio(1);
            #pragma unroll
            for (int f = 0; f < 4; ++f) {
                union { bf16x4 v; unsigned int u[2]; } pb;
                pb.u[0] = pk[f][0];
                pb.u[1] = pk[f][1];
                const int voff = (((2 * f + (quad >> 1)) ^ ck) << 3) + ((quad & 1) << 2);
                #pragma unroll
                for (int dt = 0; dt < 4; ++dt) {
                    bf16x4 va = *(const bf16x4*)&vbuf[bb][(dt * 16 + col) * 64 + voff];
                    accO[dt] = MFMA16(va, pb.v, accO[dt], 0, 0, 0);
                }
            }
            __builtin_amdgcn_s_setprio(0);

            __syncthreads();
        }

        float lr = l_lane;
        lr += __shfl_xor(lr, 16);
        lr += __shfl_xor(lr, 32);
        const float inv = 1.0f / lr;

        unsigned short* dst = AO + ((size_t)b * TT + irow) * DM + h * DH + quad * 4;
        #pragma unroll
        for (int dt = 0; dt < 4; ++dt) {
            u16x4 o;
            o.x = f2b(accO[dt][0] * inv);
            o.y = f2b(accO[dt][1] * inv);
            o.z = f2b(accO[dt][2] * inv);
            o.w = f2b(accO[dt][3] * inv);
            *(u16x4*)(dst + dt * 16) = o;
        }
        __syncthreads();
    }
}

extern "C" void kernel_launch(void* const* d_in, const int* in_sizes, int n_in,
                              void* d_out, int out_size, void* d_ws, size_t ws_size,
                              hipStream_t stream) {
    const float* x  = (const float*)d_in[0];
    const float* wq = (const float*)d_in[1];
    const float* wk = (const float*)d_in[2];
    const float* wv = (const float*)d_in[3];
    const float* wo = (const float*)d_in[4];
    float* out = (float*)d_out;

    char* ws = (char*)d_ws;
    size_t off = 0;
    auto alloc = [&](size_t bytes) -> void* {
        void* p = ws + off;
        off += (bytes + 255) & ~(size_t)255;
        return p;
    };
    const int M = BB * TT; // 4096
    unsigned short* xb  = (unsigned short*)alloc((size_t)M * DM * 2);
    unsigned short* wqT = (unsigned short*)alloc((size_t)DM * DM * 2);
    unsigned short* wkT = (unsigned short*)alloc((size_t)(HKV * DH) * DM * 2);
    unsigned short* wvT = (unsigned short*)alloc((size_t)(HKV * DH) * DM * 2);
    unsigned short* woT = (unsigned short*)alloc((size_t)DM * DM * 2);
    unsigned short* qb  = (unsigned short*)alloc((size_t)BB * HH * TT * DH * 2);
    unsigned short* kb  = (unsigned short*)alloc((size_t)BB * HKV * TT * DH * 2);
    unsigned short* vtb = (unsigned short*)alloc((size_t)BB * HKV * DH * TT * 2);
    unsigned short* ao  = (unsigned short*)alloc((size_t)M * DM * 2);
    float2* rope        = (float2*)alloc((size_t)TT * 32 * sizeof(float2));

    k_pre<<<4864, 256, 0, stream>>>(x, xb, rope, wq, wk, wv, wo, wqT, wkT, wvT, woT);
    k_qkv<<<dim3(M / 128, 20), 256, 0, stream>>>(xb, wqT, wkT, wvT, qb, kb, vtb, rope);
    k_attn<<<768, 256, 0, stream>>>(qb, kb, vtb, ao);
    k_out<<<dim3(M / 128, 12), 256, 0, stream>>>(ao, woT, out);
}

// Round 13
// 61.819 us; speedup vs baseline: 2.1281x; 2.1281x over previous
//
#include <hip/hip_runtime.h>
#include <hip/hip_bf16.h>

// GQA prefill: B=2 T=2048 DM=768 H=12 HKV=4 DH=64 WIN=512 GLB=64
// 4 launches: pre | fused QKV GEMM | flash attn | out GEMM (round-9 structure).
// NEW: XCD-chunked grid mapping for both GEMMs — each XCD owns a contiguous
// x-range (4 A-tiles, 0.8MB) across ALL y, so A+weights fit its 4MB L2 and
// A streams from L3 once per chunk instead of once per y (126MB -> ~21MB L3).

typedef __attribute__((ext_vector_type(8))) short bf16x8;
typedef __attribute__((ext_vector_type(4))) short bf16x4;
typedef __attribute__((ext_vector_type(4))) float f32x4;
typedef __attribute__((ext_vector_type(4))) unsigned short u16x4;

#define MFMA   __builtin_amdgcn_mfma_f32_16x16x32_bf16
#define MFMA16 __builtin_amdgcn_mfma_f32_16x16x16bf16_1k

constexpr int BB = 2, TT = 2048, DM = 768, HH = 12, HKV = 4, DH = 64;
constexpr int WIN = 512, GLB = 64;
constexpr float SC2 = 0.18033688011112042f; // 0.125 * log2(e)

__device__ __forceinline__ unsigned short f2b(float f) {
    union { float f; unsigned int u; } v; v.f = f;
    unsigned int r = v.u + 0x7fffu + ((v.u >> 16) & 1u);
    return (unsigned short)(r >> 16);
}

#define GLOAD_LDS(gp, lp)                                                      \
    __builtin_amdgcn_global_load_lds(                                          \
        (const __attribute__((address_space(1))) void*)(gp),                   \
        (__attribute__((address_space(3))) void*)(lp), 16, 0, 0)

// ---------- fused prep: x->bf16 (0..3071), rope (3072..3327), W^T (3328..4863)
__global__ __launch_bounds__(256) void k_pre(const float* __restrict__ x,
                                             unsigned short* __restrict__ xb,
                                             float2* __restrict__ rope,
                                             const float* __restrict__ wq,
                                             const float* __restrict__ wk,
                                             const float* __restrict__ wv,
                                             const float* __restrict__ wo,
                                             unsigned short* __restrict__ wqT,
                                             unsigned short* __restrict__ wkT,
                                             unsigned short* __restrict__ wvT,
                                             unsigned short* __restrict__ woT) {
    __shared__ float t[32][33];
    int bid = blockIdx.x, tid = threadIdx.x;
    if (bid < 3072) {
        int i = bid * 256 + tid;
        float4 v = ((const float4*)x)[i];
        u16x4 o; o.x = f2b(v.x); o.y = f2b(v.y); o.z = f2b(v.z); o.w = f2b(v.w);
        ((u16x4*)xb)[i] = o;
        return;
    }
    if (bid < 3328) {
        int i = (bid - 3072) * 256 + tid;  // T*32
        int tt = i >> 5, p = i & 31;
        float inv = exp2f(-(float)p * (13.287712379549449f / 32.0f));
        float ang = (float)tt * inv;
        rope[i] = make_float2(cosf(ang), sinf(ang));
        return;
    }
    int wb = bid - 3328;
    const float* src; unsigned short* dst; int N, tile;
    if (wb < 576)      { src = wq; dst = wqT; N = 768; tile = wb; }
    else if (wb < 768) { src = wk; dst = wkT; N = 256; tile = wb - 576; }
    else if (wb < 960) { src = wv; dst = wvT; N = 256; tile = wb - 768; }
    else               { src = wo; dst = woT; N = 768; tile = wb - 960; }
    int ntiles = N / 32;
    int k0 = (tile / ntiles) * 32, n0 = (tile % ntiles) * 32;
    int tx = tid & 31, ty = tid >> 5;
    #pragma unroll
    for (int e = 0; e < 4; ++e) {
        int r = ty + e * 8;
        t[r][tx] = src[(size_t)(k0 + r) * N + n0 + tx];
    }
    __syncthreads();
    #pragma unroll
    for (int e = 0; e < 4; ++e) {
        int r = ty + e * 8;
        dst[(size_t)(n0 + r) * DM + k0 + tx] = f2b(t[tx][r]);
    }
}

// ---------- fused QKV GEMM: 128x64 tile, BK=64, 12 steps, XOR-swizzled LDS.
// Grid: 640 linear blocks; XCD-chunked map: xcd=bid&7 owns x in [4*xcd,4*xcd+4)
// for all 20 y -> per-XCD working set = 4 A-tiles + all weights < 4MB L2.
__global__ __launch_bounds__(256) void k_qkv(const unsigned short* __restrict__ xb,
                                             const unsigned short* __restrict__ wqT,
                                             const unsigned short* __restrict__ wkT,
                                             const unsigned short* __restrict__ wvT,
                                             unsigned short* __restrict__ qb,
                                             unsigned short* __restrict__ kb,
                                             unsigned short* __restrict__ vtb,
                                             const float2* __restrict__ rope) {
    __shared__ __align__(16) unsigned short Ab[2][128 * 64];
    __shared__ __align__(16) unsigned short Bb[2][64 * 64];
    const int tid = threadIdx.x;
    const int wave = tid >> 6, lane = tid & 63;
    const int quad = lane >> 4, col = lane & 15;
    const int bid = blockIdx.x;            // [0,640)
    const int j = bid >> 3;                // [0,80)
    const int y = j >> 2;                  // [0,20)
    const int m0b = ((bid & 7) * 4 + (j & 3)) * 128;
    int mode, hl;
    const unsigned short* Bt;
    if (y < 12)      { mode = 0; hl = y;      Bt = wqT + (size_t)hl * 64 * DM; }
    else if (y < 16) { mode = 1; hl = y - 12; Bt = wkT + (size_t)hl * 64 * DM; }
    else             { mode = 2; hl = y - 16; Bt = wvT + (size_t)hl * 64 * DM; }

    const int rg = lane >> 3;
    const int cg = (lane & 7) ^ rg;
    const int ck = col & 7;

    f32x4 acc[2][4];
    #pragma unroll
    for (int rt = 0; rt < 2; ++rt)
        #pragma unroll
        for (int jj = 0; jj < 4; ++jj) acc[rt][jj] = f32x4{0.f, 0.f, 0.f, 0.f};

    auto stage = [&](int buf, int k) {
        #pragma unroll
        for (int m = 0; m < 4; ++m) {
            int g = wave * 4 + m;
            GLOAD_LDS(xb + (size_t)(m0b + g * 8 + rg) * DM + k + cg * 8,
                      &Ab[buf][g * 512]);
        }
        #pragma unroll
        for (int m = 0; m < 2; ++m) {
            int g = wave * 2 + m;
            GLOAD_LDS(Bt + (size_t)(g * 8 + rg) * DM + k + cg * 8,
                      &Bb[buf][g * 512]);
        }
    };

    stage(0, 0);
    __syncthreads();

    const int arow0 = (wave * 32 + col) * 64;
    const int arow1 = (wave * 32 + 16 + col) * 64;

    for (int t = 0; t < 12; ++t) {
        const int buf = t & 1;
        if (t < 11) stage(buf ^ 1, (t + 1) * 64);
        __builtin_amdgcn_s_setprio(1);
        #pragma unroll
        for (int ks = 0; ks < 2; ++ks) {
            const int p = ((ks * 4 + quad) ^ ck) * 8;
            bf16x8 a0 = *(const bf16x8*)&Ab[buf][arow0 + p];
            bf16x8 a1 = *(const bf16x8*)&Ab[buf][arow1 + p];
            #pragma unroll
            for (int jj = 0; jj < 4; ++jj) {
                bf16x8 b = *(const bf16x8*)&Bb[buf][(jj * 16 + col) * 64 + p];
                acc[0][jj] = MFMA(a0, b, acc[0][jj], 0, 0, 0);
                acc[1][jj] = MFMA(a1, b, acc[1][jj], 0, 0, 0);
            }
        }
        __builtin_amdgcn_s_setprio(0);
        __syncthreads();
    }

    if (mode == 2) {
        int b = m0b >> 11;
        #pragma unroll
        for (int jj = 0; jj < 4; ++jj)
            #pragma unroll
            for (int rt = 0; rt < 2; ++rt)
                #pragma unroll
                for (int r = 0; r < 4; ++r) {
                    int m = m0b + wave * 32 + rt * 16 + quad * 4 + r;
                    int t = m & (TT - 1);
                    int d = jj * 16 + col;
                    vtb[((size_t)(b * HKV + hl) * DH + d) * TT + t] = f2b(acc[rt][jj][r]);
                }
        return;
    }
    int nheads = (mode == 0) ? HH : HKV;
    unsigned short* ob = (mode == 0) ? qb : kb;
    #pragma unroll
    for (int rt = 0; rt < 2; ++rt)
        #pragma unroll
        for (int r = 0; r < 4; ++r) {
            int m = m0b + wave * 32 + rt * 16 + quad * 4 + r;
            int t = m & (TT - 1);
            int b = m >> 11;
            float2 cs0 = rope[t * 32 + col];
            float2 cs1 = rope[t * 32 + 16 + col];
            float v0 = acc[rt][0][r], v1 = acc[rt][1][r], v2 = acc[rt][2][r], v3 = acc[rt][3][r];
            unsigned short* dst = ob + ((size_t)(b * nheads + hl) * TT + t) * DH + col;
            dst[0]  = f2b(v0 * cs0.x - v2 * cs0.y);
            dst[16] = f2b(v1 * cs1.x - v3 * cs1.y);
            dst[32] = f2b(v2 * cs0.x + v0 * cs0.y);
            dst[48] = f2b(v3 * cs1.x + v1 * cs1.y);
        }
}

// ---------- output projection GEMM (f32 out), same structure, XCD-chunked map.
// Grid: 384 linear; xcd=bid&7 owns x in [4*xcd,..+4) for all 12 n0-slices.
__global__ __launch_bounds__(256) void k_out(const unsigned short* __restrict__ ao,
                                             const unsigned short* __restrict__ woT,
                                             float* __restrict__ out) {
    __shared__ __align__(16) unsigned short Ab[2][128 * 64];
    __shared__ __align__(16) unsigned short Bb[2][64 * 64];
    const int tid = threadIdx.x;
    const int wave = tid >> 6, lane = tid & 63;
    const int quad = lane >> 4, col = lane & 15;
    const int bid = blockIdx.x;            // [0,384)
    const int j = bid >> 3;                // [0,48)
    const int n0 = (j >> 2) * 64;          // [0,12)*64
    const int m0b = ((bid & 7) * 4 + (j & 3)) * 128;

    const int rg = lane >> 3;
    const int cg = (lane & 7) ^ rg;
    const int ck = col & 7;

    f32x4 acc[2][4];
    #pragma unroll
    for (int rt = 0; rt < 2; ++rt)
        #pragma unroll
        for (int jj = 0; jj < 4; ++jj) acc[rt][jj] = f32x4{0.f, 0.f, 0.f, 0.f};

    auto stage = [&](int buf, int k) {
        #pragma unroll
        for (int m = 0; m < 4; ++m) {
            int g = wave * 4 + m;
            GLOAD_LDS(ao + (size_t)(m0b + g * 8 + rg) * DM + k + cg * 8,
                      &Ab[buf][g * 512]);
        }
        #pragma unroll
        for (int m = 0; m < 2; ++m) {
            int g = wave * 2 + m;
            GLOAD_LDS(woT + (size_t)(n0 + g * 8 + rg) * DM + k + cg * 8,
                      &Bb[buf][g * 512]);
        }
    };

    stage(0, 0);
    __syncthreads();

    const int arow0 = (wave * 32 + col) * 64;
    const int arow1 = (wave * 32 + 16 + col) * 64;

    for (int t = 0; t < 12; ++t) {
        const int buf = t & 1;
        if (t < 11) stage(buf ^ 1, (t + 1) * 64);
        __builtin_amdgcn_s_setprio(1);
        #pragma unroll
        for (int ks = 0; ks < 2; ++ks) {
            const int p = ((ks * 4 + quad) ^ ck) * 8;
            bf16x8 a0 = *(const bf16x8*)&Ab[buf][arow0 + p];
            bf16x8 a1 = *(const bf16x8*)&Ab[buf][arow1 + p];
            #pragma unroll
            for (int jj = 0; jj < 4; ++jj) {
                bf16x8 b = *(const bf16x8*)&Bb[buf][(jj * 16 + col) * 64 + p];
                acc[0][jj] = MFMA(a0, b, acc[0][jj], 0, 0, 0);
                acc[1][jj] = MFMA(a1, b, acc[1][jj], 0, 0, 0);
            }
        }
        __builtin_amdgcn_s_setprio(0);
        __syncthreads();
    }

    #pragma unroll
    for (int rt = 0; rt < 2; ++rt)
        #pragma unroll
        for (int jj = 0; jj < 4; ++jj)
            #pragma unroll
            for (int r = 0; r < 4; ++r) {
                int m = m0b + wave * 32 + rt * 16 + quad * 4 + r;
                out[(size_t)m * DM + n0 + jj * 16 + col] = acc[rt][jj][r];
            }
}

// ---------- flash attention: 4 waves x 16 q-rows, gload_lds KV staging,
// swapped QK^T, zero-shuffle PV (round-9 structure, best measured).
__global__ __launch_bounds__(256) void k_attn(const unsigned short* __restrict__ Q,
                                              const unsigned short* __restrict__ K,
                                              const unsigned short* __restrict__ Vt,
                                              unsigned short* __restrict__ AO) {
    __shared__ __align__(16) unsigned short kbuf[2][64 * 64]; // [buf][j][d] 8KB
    __shared__ __align__(16) unsigned short vbuf[2][64 * 64]; // [buf][d][j] 8KB
    const int lane = threadIdx.x & 63;
    const int wave = threadIdx.x >> 6;
    const int quad = lane >> 4, col = lane & 15;
    // bijective XCD swizzle: 768 blocks = 8 XCDs x 96
    const int lbid = (blockIdx.x & 7) * 96 + (blockIdx.x >> 3);
    const int qb = lbid & 31, bh = lbid >> 5;
    const int h = bh % HH, b = bh / HH;
    const int hkv = h / 3;
    const int i0 = qb * 64 + wave * 16;
    const int irow = i0 + col;

    const unsigned short* qbase = Q + ((size_t)(b * HH + h) * TT + irow) * DH + quad * 8;
    const bf16x8 qf0 = *(const bf16x8*)qbase;
    const bf16x8 qf1 = *(const bf16x8*)(qbase + 32);
    const unsigned short* kbase = K + (size_t)(b * HKV + hkv) * TT * DH;
    const unsigned short* vbase = Vt + (size_t)(b * HKV + hkv) * DH * TT;

    float m_run = -1e30f, l_lane = 0.f;
    f32x4 accO[4];
    #pragma unroll
    for (int dt = 0; dt < 4; ++dt) accO[dt] = f32x4{0.f, 0.f, 0.f, 0.f};

    int jw0 = (qb * 64 - WIN + 1) & ~63; if (jw0 < 64) jw0 = 64;
    const int jlast = qb * 64;
    const int nt = 1 + ((jlast >= 64) ? (((jlast - jw0) >> 6) + 1) : 0);
    auto j0_of = [&](int t) { return (t == 0) ? 0 : (jw0 + ((t - 1) << 6)); };

    const int sr = lane >> 3;
    const int soff = ((lane & 7) ^ sr) * 8;
    const int ck = col & 7;

    auto stage = [&](int bb, int j0) {
        GLOAD_LDS(kbase + (size_t)(j0 + wave * 16 + sr) * DH + soff,
                  &kbuf[bb][(wave * 16) * 64]);
        GLOAD_LDS(kbase + (size_t)(j0 + wave * 16 + 8 + sr) * DH + soff,
                  &kbuf[bb][(wave * 16 + 8) * 64]);
        GLOAD_LDS(vbase + (size_t)(wave * 16 + sr) * TT + j0 + soff,
                  &vbuf[bb][(wave * 16) * 64]);
        GLOAD_LDS(vbase + (size_t)(wave * 16 + 8 + sr) * TT + j0 + soff,
                  &vbuf[bb][(wave * 16 + 8) * 64]);
    };

    stage(0, 0);
    __syncthreads();

    for (int t = 0; t < nt; ++t) {
        const int bb = t & 1;
        if (t + 1 < nt) stage(bb ^ 1, j0_of(t + 1));

        const int j0 = j0_of(t);
        const int mode = (t == 0) ? ((i0 < 64) ? 1 : 0)
                       : (((j0 + 63 > i0) || (j0 <= i0 + 15 - WIN)) ? 2 : 0);

        f32x4 sT[4];
        #pragma unroll
        for (int f = 0; f < 4; ++f) sT[f] = f32x4{0.f, 0.f, 0.f, 0.f};
        __builtin_amdgcn_s_setprio(1);
        #pragma unroll
        for (int f = 0; f < 4; ++f) {
            bf16x8 k0 = *(const bf16x8*)&kbuf[bb][(f * 16 + col) * 64 + (quad ^ ck) * 8];
            bf16x8 k1 = *(const bf16x8*)&kbuf[bb][(f * 16 + col) * 64 + ((4 + quad) ^ ck) * 8];
            sT[f] = MFMA(k0, qf0, sT[f], 0, 0, 0);
            sT[f] = MFMA(k1, qf1, sT[f], 0, 0, 0);
        }
        __builtin_amdgcn_s_setprio(0);

        const int dq = irow - j0 - quad * 4;
        if (mode == 1) {
            #pragma unroll
            for (int f = 0; f < 4; ++f)
                #pragma unroll
                for (int r = 0; r < 4; ++r)
                    if (dq - f * 16 - r < 0) sT[f][r] = -3e30f;
        } else if (mode == 2) {
            #pragma unroll
            for (int f = 0; f < 4; ++f)
                #pragma unroll
                for (int r = 0; r < 4; ++r)
                    if ((unsigned)(dq - f * 16 - r) >= (unsigned)WIN) sT[f][r] = -3e30f;
        }

        float mx = -3e30f;
        #pragma unroll
        for (int f = 0; f < 4; ++f)
            #pragma unroll
            for (int r = 0; r < 4; ++r) mx = fmaxf(mx, sT[f][r]);

        if (!__all(mx <= m_run + 44.f)) {
            float rm = fmaxf(mx, __shfl_xor(mx, 16));
            rm = fmaxf(rm, __shfl_xor(rm, 32));
            float mn = fmaxf(m_run, rm);
            float corr = exp2f((m_run - mn) * SC2);
            m_run = mn;
            l_lane *= corr;
            #pragma unroll
            for (int dt = 0; dt < 4; ++dt)
                #pragma unroll
                for (int r = 0; r < 4; ++r) accO[dt][r] *= corr;
        }

        const float mbase = m_run * SC2;
        unsigned int pk[4][2];
        float ps = 0.f;
        #pragma unroll
        for (int f = 0; f < 4; ++f) {
            float p0 = exp2f(__builtin_fmaf(sT[f][0], SC2, -mbase));
            float p1 = exp2f(__builtin_fmaf(sT[f][1], SC2, -mbase));
            float p2 = exp2f(__builtin_fmaf(sT[f][2], SC2, -mbase));
            float p3 = exp2f(__builtin_fmaf(sT[f][3], SC2, -mbase));
            ps += (p0 + p1) + (p2 + p3);
            asm("v_cvt_pk_bf16_f32 %0, %1, %2" : "=v"(pk[f][0]) : "v"(p0), "v"(p1));
            asm("v_cvt_pk_bf16_f32 %0, %1, %2" : "=v"(pk[f][1]) : "v"(p2), "v"(p3));
        }
        l_lane += ps;

        __builtin_amdgcn_s_setprio(1);
        #pragma unroll
        for (int f = 0; f < 4; ++f) {
            union { bf16x4 v; unsigned int u[2]; } pb;
            pb.u[0] = pk[f][0];
            pb.u[1] = pk[f][1];
            const int voff = (((2 * f + (quad >> 1)) ^ ck) << 3) + ((quad & 1) << 2);
            #pragma unroll
            for (int dt = 0; dt < 4; ++dt) {
                bf16x4 va = *(const bf16x4*)&vbuf[bb][(dt * 16 + col) * 64 + voff];
                accO[dt] = MFMA16(va, pb.v, accO[dt], 0, 0, 0);
            }
        }
        __builtin_amdgcn_s_setprio(0);

        __syncthreads();
    }

    float lr = l_lane;
    lr += __shfl_xor(lr, 16);
    lr += __shfl_xor(lr, 32);
    const float inv = 1.0f / lr;

    unsigned short* dst = AO + ((size_t)b * TT + irow) * DM + h * DH + quad * 4;
    #pragma unroll
    for (int dt = 0; dt < 4; ++dt) {
        u16x4 o;
        o.x = f2b(accO[dt][0] * inv);
        o.y = f2b(accO[dt][1] * inv);
        o.z = f2b(accO[dt][2] * inv);
        o.w = f2b(accO[dt][3] * inv);
        *(u16x4*)(dst + dt * 16) = o;
    }
}

extern "C" void kernel_launch(void* const* d_in, const int* in_sizes, int n_in,
                              void* d_out, int out_size, void* d_ws, size_t ws_size,
                              hipStream_t stream) {
    const float* x  = (const float*)d_in[0];
    const float* wq = (const float*)d_in[1];
    const float* wk = (const float*)d_in[2];
    const float* wv = (const float*)d_in[3];
    const float* wo = (const float*)d_in[4];
    float* out = (float*)d_out;

    char* ws = (char*)d_ws;
    size_t off = 0;
    auto alloc = [&](size_t bytes) -> void* {
        void* p = ws + off;
        off += (bytes + 255) & ~(size_t)255;
        return p;
    };
    const int M = BB * TT; // 4096
    unsigned short* xb  = (unsigned short*)alloc((size_t)M * DM * 2);
    unsigned short* wqT = (unsigned short*)alloc((size_t)DM * DM * 2);
    unsigned short* wkT = (unsigned short*)alloc((size_t)(HKV * DH) * DM * 2);
    unsigned short* wvT = (unsigned short*)alloc((size_t)(HKV * DH) * DM * 2);
    unsigned short* woT = (unsigned short*)alloc((size_t)DM * DM * 2);
    unsigned short* qb  = (unsigned short*)alloc((size_t)BB * HH * TT * DH * 2);
    unsigned short* kb  = (unsigned short*)alloc((size_t)BB * HKV * TT * DH * 2);
    unsigned short* vtb = (unsigned short*)alloc((size_t)BB * HKV * DH * TT * 2);
    unsigned short* ao  = (unsigned short*)alloc((size_t)M * DM * 2);
    float2* rope        = (float2*)alloc((size_t)TT * 32 * sizeof(float2));

    k_pre<<<4864, 256, 0, stream>>>(x, xb, rope, wq, wk, wv, wo, wqT, wkT, wvT, woT);
    k_qkv<<<640, 256, 0, stream>>>(xb, wqT, wkT, wvT, qb, kb, vtb, rope);
    k_attn<<<768, 256, 0, stream>>>(qb, kb, vtb, ao);
    k_out<<<384, 256, 0, stream>>>(ao, woT, out);
}